// Round 6
// baseline (1553.531 us; speedup 1.0000x reference)
//
#include <hip/hip_runtime.h>
#include <math.h>

#define B_ 32
#define S_ 511
#define T_ 512
#define D_ 512
#define H_ 8
#define HD_ 64
#define L_ 4
#define P_ 501
#define PD_ 32
#define FD_ 448
#define DFF_ 2048

typedef __attribute__((ext_vector_type(8))) short bf16x8;
typedef __attribute__((ext_vector_type(4))) float f32x4;

#define GLDS16(gp, lp) __builtin_amdgcn_global_load_lds(                      \
    (const __attribute__((address_space(1))) void*)(gp),                      \
    (__attribute__((address_space(3))) void*)(lp), 16, 0, 0)

__device__ __forceinline__ unsigned short f2bf(float f) {
  union { float f; unsigned int u; } c; c.f = f;
  unsigned int r = c.u + 0x7FFFu + ((c.u >> 16) & 1u);  // RNE
  return (unsigned short)(r >> 16);
}

// ---------------- weight transpose+convert: fp32 [K][N] -> bf16 [N][K] ----------------
__global__ __launch_bounds__(256) void wtrans_kernel(
    const float* __restrict__ in, unsigned short* __restrict__ out, int K, int N)
{
  __shared__ float t[64][65];
  const int l = blockIdx.z;
  in  += (size_t)l * K * N;
  out += (size_t)l * N * K;
  const int k0 = blockIdx.x * 64, n0 = blockIdx.y * 64;
  const int tx = threadIdx.x & 63, ty = threadIdx.x >> 6;
#pragma unroll
  for (int i = 0; i < 16; ++i) {
    int r = ty + i * 4;
    t[r][tx] = in[(size_t)(k0 + r) * N + n0 + tx];
  }
  __syncthreads();
#pragma unroll
  for (int i = 0; i < 16; ++i) {
    int r = ty + i * 4;
    out[(size_t)(n0 + r) * K + k0 + tx] = f2bf(t[tx][r]);
  }
}

// ---------------- embedding + positional encoding (dual write fp32 + bf16) ----------------
__global__ __launch_bounds__(256) void embed_kernel(
    const float* __restrict__ runs, const float* __restrict__ wickets,
    const float* __restrict__ overs, const int* __restrict__ batters,
    const int* __restrict__ bowlers, const float* __restrict__ pemb,
    const float* __restrict__ Wf, const float* __restrict__ bfv,
    const float* __restrict__ qtok, float* __restrict__ x,
    unsigned short* __restrict__ xb)
{
  size_t idx = (size_t)blockIdx.x * 256 + threadIdx.x;
  const size_t total = (size_t)B_ * T_ * D_;
  if (idx >= total) return;
  int d = (int)(idx % D_);
  int t = (int)((idx / D_) % T_);
  int b = (int)(idx / ((size_t)D_ * T_));
  float val;
  if (t < S_) {
    size_t st = (size_t)b * S_ + t;
    if (d < FD_) {
      val = runs[st] * Wf[d] + wickets[st] * Wf[FD_ + d] + overs[st] * Wf[2 * FD_ + d] + bfv[d];
    } else if (d < FD_ + PD_) {
      val = pemb[(size_t)batters[st] * PD_ + (d - FD_)];
    } else {
      val = pemb[(size_t)bowlers[st] * PD_ + (d - FD_ - PD_)];
    }
  } else {
    val = qtok[d];
  }
  float div = expf((float)(2 * (d >> 1)) * (-9.210340371976184f / (float)D_));
  float ang = (float)t * div;
  val += (d & 1) ? cosf(ang) : sinf(ang);
  x[idx] = val;
  xb[idx] = f2bf(val);
}

// ---------------- bf16 MFMA GEMM (global_load_lds staging) ----------------
// ACT==0: fp32 C ; ACT==1: GELU -> bf16 Cb ; ACT==2: bf16 Cb ; ACT==3: bf16 -> vt[B,H,64,T]
template<int ACT>
__global__ __launch_bounds__(256) void mfma_gemm(
    const unsigned short* __restrict__ A, const unsigned short* __restrict__ Bt,
    const float* __restrict__ bias, float* __restrict__ C,
    unsigned short* __restrict__ Cb, int N, int K)
{
  __shared__ unsigned short As[128 * 32];
  __shared__ unsigned short Bs[128 * 32];
  const int tid = threadIdx.x;
  const int m0 = blockIdx.y * 128, n0 = blockIdx.x * 128;
  const int lane = tid & 63, w = tid >> 6;
  const int wr = w >> 1, wc = w & 1;
  const int lr = lane & 15, lg = lane >> 4;

  f32x4 acc[4][4] = {};

  // staging: wave w covers rows [16w,16w+16) and [64+16w,64+16w+16); lane l -> row 16w+(l>>2), col8 (l&3)*8
  const int srow = w * 16 + (lane >> 2);
  const int sc8 = (lane & 3) * 8;
  const unsigned short* gA0 = A + (size_t)(m0 + srow) * K + sc8;
  const unsigned short* gA1 = gA0 + (size_t)64 * K;
  const unsigned short* gB0 = Bt + (size_t)(n0 + srow) * K + sc8;
  const unsigned short* gB1 = gB0 + (size_t)64 * K;
  unsigned short* lA0 = &As[(w * 16) * 32];
  unsigned short* lA1 = &As[(64 + w * 16) * 32];
  unsigned short* lB0 = &Bs[(w * 16) * 32];
  unsigned short* lB1 = &Bs[(64 + w * 16) * 32];

  for (int k0 = 0; k0 < K; k0 += 32) {
    GLDS16(gA0 + k0, lA0);
    GLDS16(gA1 + k0, lA1);
    GLDS16(gB0 + k0, lB0);
    GLDS16(gB1 + k0, lB1);
    __syncthreads();  // compiler drains vmcnt before barrier -> tile visible
    bf16x8 af[4], bfr[4];
#pragma unroll
    for (int f = 0; f < 4; ++f) {
      af[f]  = *(const bf16x8*)&As[(wr * 64 + f * 16 + lr) * 32 + lg * 8];
      bfr[f] = *(const bf16x8*)&Bs[(wc * 64 + f * 16 + lr) * 32 + lg * 8];
    }
#pragma unroll
    for (int i = 0; i < 4; ++i)
#pragma unroll
      for (int j = 0; j < 4; ++j)
        acc[i][j] = __builtin_amdgcn_mfma_f32_16x16x32_bf16(af[i], bfr[j], acc[i][j], 0, 0, 0);
    __syncthreads();  // protect next iteration's overwrite
  }

  const int crow0 = m0 + wr * 64 + lg * 4;
  const int ccol0 = n0 + wc * 64 + lr;
#pragma unroll
  for (int i = 0; i < 4; ++i) {
#pragma unroll
    for (int j = 0; j < 4; ++j) {
      const int col = ccol0 + j * 16;
      const float bcol = bias[col];
#pragma unroll
      for (int r = 0; r < 4; ++r) {
        const int row = crow0 + i * 16 + r;
        float v = acc[i][j][r] + bcol;
        if (ACT == 1) {
          v = 0.5f * v * (1.0f + erff(v * 0.70710678118654752f));
          Cb[(size_t)row * N + col] = f2bf(v);
        } else if (ACT == 2) {
          Cb[(size_t)row * N + col] = f2bf(v);
        } else if (ACT == 3) {
          const int t = row & (T_ - 1), bb = row >> 9;
          const int hh = col >> 6, hd = col & 63;
          Cb[(((size_t)bb * H_ + hh) * HD_ + hd) * T_ + t] = f2bf(v);
        } else {
          C[(size_t)row * N + col] = v;
        }
      }
    }
  }
}

// ---------------- MFMA flash attention, 128-row Q tile ----------------
// block = (qt, h, b), 4 waves; wave w owns q rows [w*32, w*32+32) as two 16-row m-frags
__global__ __launch_bounds__(256) void flash_mfma_kernel(
    const unsigned short* __restrict__ q, const unsigned short* __restrict__ k,
    const unsigned short* __restrict__ vt, unsigned short* __restrict__ o,
    const int* __restrict__ batters, const int* __restrict__ bowlers,
    const float* __restrict__ rec_sp, const float* __restrict__ bow_sp,
    const float* __restrict__ bat_sp, int l)
{
  __shared__ unsigned short QPs[128 * 70];  // Q tile, later P tile (wave-private rows)
  __shared__ unsigned short Ks[64 * 70];
  __shared__ unsigned short Vs[64 * 70];    // V^T tile: [d][k]
  __shared__ int aq_s[128], ak_s[64];

  const int qt = blockIdx.x, h = blockIdx.y, b = blockIdx.z;
  const int tid = threadIdx.x;
  const int w = tid >> 6, lane = tid & 63;
  const int c = lane & 15, g = lane >> 4;
  const int q0 = qt * 128;

  int mode = 0; float hs = 0.f;
  if (h == 0) { mode = 1; hs = rec_sp[l]; }
  else if (h == 1) { mode = 2; hs = bow_sp[l]; }
  else if (h == 2) { mode = 3; hs = bat_sp[l]; }
  const int* actors = (mode == 2) ? bowlers : batters;

  const int sr = tid >> 2, sch = (tid & 3) * 16;

  // stage Q tile [128 q][64 d]
#pragma unroll
  for (int half = 0; half < 2; ++half) {
    const unsigned short* src = q + ((size_t)b * T_ + q0 + half * 64 + sr) * D_ + h * HD_ + sch;
    *(bf16x8*)&QPs[(half * 64 + sr) * 70 + sch]     = *(const bf16x8*)src;
    *(bf16x8*)&QPs[(half * 64 + sr) * 70 + sch + 8] = *(const bf16x8*)(src + 8);
  }
  if (tid < 128) {
    int qg_ = q0 + tid;
    aq_s[tid] = (mode >= 2 && qg_ < S_) ? actors[(size_t)b * S_ + qg_] : -1;
  }
  __syncthreads();

  // Q A-fragments in regs for whole kernel
  bf16x8 af[2][2];
#pragma unroll
  for (int m = 0; m < 2; ++m) {
    af[m][0] = *(const bf16x8*)&QPs[(w * 32 + m * 16 + c) * 70 + g * 8];
    af[m][1] = *(const bf16x8*)&QPs[(w * 32 + m * 16 + c) * 70 + 32 + g * 8];
  }
  int aq4[2][4];
#pragma unroll
  for (int m = 0; m < 2; ++m)
#pragma unroll
    for (int r = 0; r < 4; ++r) aq4[m][r] = aq_s[w * 32 + m * 16 + 4 * g + r];

  float m_r[2][4], l_r[2][4];
#pragma unroll
  for (int m = 0; m < 2; ++m)
#pragma unroll
    for (int r = 0; r < 4; ++r) { m_r[m][r] = -INFINITY; l_r[m][r] = 0.f; }
  f32x4 o_acc[2][4] = {};

  const int ktmax = 2 * qt + 1;
  for (int kt = 0; kt <= ktmax; ++kt) {
    const int k0 = kt * 64;
    __syncthreads();  // prior readers of Ks/Vs/ak_s done
    {
      const unsigned short* ksrc = k + ((size_t)b * T_ + k0 + sr) * D_ + h * HD_ + sch;
      *(bf16x8*)&Ks[sr * 70 + sch]     = *(const bf16x8*)ksrc;
      *(bf16x8*)&Ks[sr * 70 + sch + 8] = *(const bf16x8*)(ksrc + 8);
      const unsigned short* vsrc = vt + ((size_t)(b * H_ + h) * HD_ + sr) * T_ + k0 + sch;
      *(bf16x8*)&Vs[sr * 70 + sch]     = *(const bf16x8*)vsrc;
      *(bf16x8*)&Vs[sr * 70 + sch + 8] = *(const bf16x8*)(vsrc + 8);
    }
    if (tid < 64) {
      int kg_ = k0 + tid;
      ak_s[tid] = (mode >= 2 && kg_ < S_) ? actors[(size_t)b * S_ + kg_] : -1;
    }
    __syncthreads();

    if (q0 + w * 32 + 31 < k0) continue;  // wave fully causal-masked for this K tile

    // ---- QK^T: S[32 q][64 k] per wave ----
    f32x4 s[2][4] = {};
#pragma unroll
    for (int f = 0; f < 4; ++f) {
      bf16x8 b0 = *(const bf16x8*)&Ks[(f * 16 + c) * 70 + g * 8];
      bf16x8 b1 = *(const bf16x8*)&Ks[(f * 16 + c) * 70 + 32 + g * 8];
#pragma unroll
      for (int m = 0; m < 2; ++m) {
        s[m][f] = __builtin_amdgcn_mfma_f32_16x16x32_bf16(af[m][0], b0, s[m][f], 0, 0, 0);
        s[m][f] = __builtin_amdgcn_mfma_f32_16x16x32_bf16(af[m][1], b1, s[m][f], 0, 0, 0);
      }
    }

    int ak4[4];
#pragma unroll
    for (int f = 0; f < 4; ++f) ak4[f] = ak_s[f * 16 + c];

#pragma unroll
    for (int m = 0; m < 2; ++m) {
      // scale + head bias + causal mask (C-layout: row=4g+r, col=f*16+c)
      float sv[4][4];
#pragma unroll
      for (int f = 0; f < 4; ++f) {
        const int kg = k0 + f * 16 + c;
#pragma unroll
        for (int r = 0; r < 4; ++r) {
          const int qg = q0 + w * 32 + m * 16 + 4 * g + r;
          float val = s[m][f][r] * 0.125f;
          if (mode == 1) {
            val = fmaf(hs, (float)kg * (1.0f / (float)T_), val);
          } else if (mode >= 2) {
            float eq = (qg == S_ || kg == S_) ? 1.0f : ((aq4[m][r] == ak4[f]) ? 1.0f : 0.0f);
            val = fmaf(hs, eq, val);
          }
          if (kg > qg) val = -INFINITY;
          sv[f][r] = val;
        }
      }
      // online softmax: rows live on 16 lanes sharing g
      float cr[4];
#pragma unroll
      for (int r = 0; r < 4; ++r) {
        float pm = fmaxf(fmaxf(sv[0][r], sv[1][r]), fmaxf(sv[2][r], sv[3][r]));
        pm = fmaxf(pm, __shfl_xor(pm, 1));
        pm = fmaxf(pm, __shfl_xor(pm, 2));
        pm = fmaxf(pm, __shfl_xor(pm, 4));
        pm = fmaxf(pm, __shfl_xor(pm, 8));
        float m_new = fmaxf(m_r[m][r], pm);
        cr[r] = __expf(m_r[m][r] - m_new);
        m_r[m][r] = m_new;
      }
      float rs[4] = {0.f, 0.f, 0.f, 0.f};
#pragma unroll
      for (int f = 0; f < 4; ++f) {
#pragma unroll
        for (int r = 0; r < 4; ++r) {
          float p = __expf(sv[f][r] - m_r[m][r]);
          rs[r] += p;
          QPs[(w * 32 + m * 16 + 4 * g + r) * 70 + f * 16 + c] = f2bf(p);
        }
      }
#pragma unroll
      for (int r = 0; r < 4; ++r) {
        float t = rs[r];
        t += __shfl_xor(t, 1);
        t += __shfl_xor(t, 2);
        t += __shfl_xor(t, 4);
        t += __shfl_xor(t, 8);
        l_r[m][r] = l_r[m][r] * cr[r] + t;
#pragma unroll
        for (int f = 0; f < 4; ++f) o_acc[m][f][r] *= cr[r];
      }
    }

    // ---- PV: O[32 q][64 d] += P @ V^T ----
    bf16x8 pa[2][2];
#pragma unroll
    for (int m = 0; m < 2; ++m) {
      pa[m][0] = *(const bf16x8*)&QPs[(w * 32 + m * 16 + c) * 70 + g * 8];
      pa[m][1] = *(const bf16x8*)&QPs[(w * 32 + m * 16 + c) * 70 + 32 + g * 8];
    }
#pragma unroll
    for (int f = 0; f < 4; ++f) {
      bf16x8 v0 = *(const bf16x8*)&Vs[(f * 16 + c) * 70 + g * 8];
      bf16x8 v1 = *(const bf16x8*)&Vs[(f * 16 + c) * 70 + 32 + g * 8];
#pragma unroll
      for (int m = 0; m < 2; ++m) {
        o_acc[m][f] = __builtin_amdgcn_mfma_f32_16x16x32_bf16(pa[m][0], v0, o_acc[m][f], 0, 0, 0);
        o_acc[m][f] = __builtin_amdgcn_mfma_f32_16x16x32_bf16(pa[m][1], v1, o_acc[m][f], 0, 0, 0);
      }
    }
  }

  // ---- epilogue: normalize, store bf16 ----
#pragma unroll
  for (int m = 0; m < 2; ++m) {
#pragma unroll
    for (int r = 0; r < 4; ++r) {
      const float inv = 1.0f / l_r[m][r];
      const int row = q0 + w * 32 + m * 16 + 4 * g + r;
#pragma unroll
      for (int f = 0; f < 4; ++f)
        o[((size_t)b * T_ + row) * D_ + h * HD_ + f * 16 + c] = f2bf(o_acc[m][f][r] * inv);
    }
  }
}

// ---------------- residual add + LayerNorm (dual write fp32 + bf16) ----------------
__global__ __launch_bounds__(256) void add_ln_kernel(
    float* __restrict__ x, const float* __restrict__ y,
    const float* __restrict__ g, const float* __restrict__ be,
    unsigned short* __restrict__ xb)
{
  int row = blockIdx.x;
  int tid = threadIdx.x;
  size_t base = (size_t)row * D_;
  float v0 = x[base + tid] + y[base + tid];
  float v1 = x[base + tid + 256] + y[base + tid + 256];
  float s = v0 + v1;
  float s2 = v0 * v0 + v1 * v1;
  __shared__ float redA[4], redB[4];
#pragma unroll
  for (int off = 32; off > 0; off >>= 1) {
    s  += __shfl_down(s, off);
    s2 += __shfl_down(s2, off);
  }
  if ((tid & 63) == 0) { redA[tid >> 6] = s; redB[tid >> 6] = s2; }
  __syncthreads();
  float st  = redA[0] + redA[1] + redA[2] + redA[3];
  float s2t = redB[0] + redB[1] + redB[2] + redB[3];
  float mu = st * (1.0f / (float)D_);
  float var = s2t * (1.0f / (float)D_) - mu * mu;
  float r = rsqrtf(var + 1e-5f);
  float o0 = (v0 - mu) * r * g[tid] + be[tid];
  float o1 = (v1 - mu) * r * g[tid + 256] + be[tid + 256];
  x[base + tid]        = o0;
  x[base + tid + 256]  = o1;
  xb[base + tid]       = f2bf(o0);
  xb[base + tid + 256] = f2bf(o1);
}

// ---------------- final: out[b,:] = x[b,T-1,:] @ Wout + bout ----------------
__global__ __launch_bounds__(256) void final_kernel(
    const float* __restrict__ x, const float* __restrict__ Wout,
    const float* __restrict__ bout, float* __restrict__ out)
{
  __shared__ float xs[D_];
  int b = blockIdx.x;
  int n = blockIdx.y * 256 + threadIdx.x;
  const float* xr = x + ((size_t)b * T_ + (T_ - 1)) * D_;
  xs[threadIdx.x] = xr[threadIdx.x];
  xs[threadIdx.x + 256] = xr[threadIdx.x + 256];
  __syncthreads();
  float acc = bout[n];
  for (int kk = 0; kk < D_; ++kk)
    acc = fmaf(xs[kk], Wout[(size_t)kk * D_ + n], acc);
  out[(size_t)b * D_ + n] = acc;
}

extern "C" void kernel_launch(void* const* d_in, const int* in_sizes, int n_in,
                              void* d_out, int out_size, void* d_ws, size_t ws_size,
                              hipStream_t stream)
{
  const float* runs    = (const float*)d_in[0];
  const float* wickets = (const float*)d_in[1];
  const float* overs   = (const float*)d_in[2];
  const int*   batters = (const int*)d_in[3];
  const int*   bowlers = (const int*)d_in[4];
  const float* pemb    = (const float*)d_in[5];
  const float* Wf      = (const float*)d_in[6];
  const float* bfv     = (const float*)d_in[7];
  const float* qtok    = (const float*)d_in[8];
  const float* Wq      = (const float*)d_in[9];
  const float* bq      = (const float*)d_in[10];
  const float* Wk      = (const float*)d_in[11];
  const float* bk      = (const float*)d_in[12];
  const float* Wv      = (const float*)d_in[13];
  const float* bv      = (const float*)d_in[14];
  const float* Wo      = (const float*)d_in[15];
  const float* bo      = (const float*)d_in[16];
  const float* rec_s   = (const float*)d_in[17];
  const float* bow_s   = (const float*)d_in[18];
  const float* bat_s   = (const float*)d_in[19];
  const float* W1      = (const float*)d_in[20];
  const float* b1      = (const float*)d_in[21];
  const float* W2      = (const float*)d_in[22];
  const float* b2      = (const float*)d_in[23];
  const float* g1      = (const float*)d_in[24];
  const float* be1     = (const float*)d_in[25];
  const float* g2      = (const float*)d_in[26];
  const float* be2     = (const float*)d_in[27];
  const float* Wout    = (const float*)d_in[28];
  const float* bout    = (const float*)d_in[29];

  float* ws = (float*)d_ws;
  const size_t n1 = (size_t)B_ * T_ * D_;  // 8M elements
  float* x  = ws;                                   // n1 f32
  float* yb = ws + n1;                              // n1 f32
  unsigned short* xb   = (unsigned short*)(ws + 2 * n1);
  unsigned short* qb16 = xb + n1;
  unsigned short* kb16 = qb16 + n1;
  unsigned short* vb16 = kb16 + n1;   // unused (V goes straight to vt)
  unsigned short* vt   = vb16 + n1;
  unsigned short* ob   = vt + n1;
  unsigned short* wt   = ob + n1;
  unsigned short* hb   = qb16;  // FFN hidden aliases qb16..vt (exactly 4*n1 shorts)

  const size_t wsz = (size_t)L_ * D_ * D_;
  unsigned short* wtq = wt;
  unsigned short* wtk = wtq + wsz;
  unsigned short* wtv = wtk + wsz;
  unsigned short* wto = wtv + wsz;
  unsigned short* wt1 = wto + wsz;
  unsigned short* wt2 = wt1 + (size_t)L_ * D_ * DFF_;

  const int M = B_ * T_;
  dim3 blk(256);

  wtrans_kernel<<<dim3(8, 8, L_),  blk, 0, stream>>>(Wq, wtq, D_, D_);
  wtrans_kernel<<<dim3(8, 8, L_),  blk, 0, stream>>>(Wk, wtk, D_, D_);
  wtrans_kernel<<<dim3(8, 8, L_),  blk, 0, stream>>>(Wv, wtv, D_, D_);
  wtrans_kernel<<<dim3(8, 8, L_),  blk, 0, stream>>>(Wo, wto, D_, D_);
  wtrans_kernel<<<dim3(8, 32, L_), blk, 0, stream>>>(W1, wt1, D_, DFF_);
  wtrans_kernel<<<dim3(32, 8, L_), blk, 0, stream>>>(W2, wt2, DFF_, D_);

  {
    size_t total = (size_t)B_ * T_ * D_;
    int nb = (int)((total + 255) / 256);
    embed_kernel<<<nb, blk, 0, stream>>>(runs, wickets, overs, batters, bowlers,
                                         pemb, Wf, bfv, qtok, x, xb);
  }

  for (int l = 0; l < L_; ++l) {
    mfma_gemm<2><<<dim3(D_ / 128, M / 128), blk, 0, stream>>>(
        xb, wtq + (size_t)l * D_ * D_, bq + l * D_, nullptr, qb16, D_, D_);
    mfma_gemm<2><<<dim3(D_ / 128, M / 128), blk, 0, stream>>>(
        xb, wtk + (size_t)l * D_ * D_, bk + l * D_, nullptr, kb16, D_, D_);
    mfma_gemm<3><<<dim3(D_ / 128, M / 128), blk, 0, stream>>>(
        xb, wtv + (size_t)l * D_ * D_, bv + l * D_, nullptr, vt, D_, D_);

    flash_mfma_kernel<<<dim3(T_ / 128, H_, B_), blk, 0, stream>>>(
        qb16, kb16, vt, ob, batters, bowlers, rec_s, bow_s, bat_s, l);

    mfma_gemm<0><<<dim3(D_ / 128, M / 128), blk, 0, stream>>>(
        ob, wto + (size_t)l * D_ * D_, bo + l * D_, yb, nullptr, D_, D_);
    add_ln_kernel<<<M, blk, 0, stream>>>(x, yb, g1 + l * D_, be1 + l * D_, xb);

    mfma_gemm<1><<<dim3(DFF_ / 128, M / 128), blk, 0, stream>>>(
        xb, wt1 + (size_t)l * D_ * DFF_, b1 + l * DFF_, nullptr, hb, DFF_, D_);
    mfma_gemm<0><<<dim3(D_ / 128, M / 128), blk, 0, stream>>>(
        hb, wt2 + (size_t)l * DFF_ * D_, b2 + l * D_, yb, nullptr, D_, DFF_);
    add_ln_kernel<<<M, blk, 0, stream>>>(x, yb, g2 + l * D_, be2 + l * D_, xb);
  }

  final_kernel<<<dim3(B_, D_ / 256), blk, 0, stream>>>(x, Wout, bout, (float*)d_out);
}

// Round 8
// 1398.820 us; speedup vs baseline: 1.1106x; 1.1106x over previous
//
#include <hip/hip_runtime.h>
#include <math.h>

#define B_ 32
#define S_ 511
#define T_ 512
#define D_ 512
#define H_ 8
#define HD_ 64
#define L_ 4
#define P_ 501
#define PD_ 32
#define FD_ 448
#define DFF_ 2048

typedef __attribute__((ext_vector_type(8))) short bf16x8;
typedef __attribute__((ext_vector_type(4))) float f32x4;

#define GLDS16(gp, lp) __builtin_amdgcn_global_load_lds(                      \
    (const __attribute__((address_space(1))) void*)(gp),                      \
    (__attribute__((address_space(3))) void*)(lp), 16, 0, 0)

__device__ __forceinline__ unsigned short f2bf(float f) {
  union { float f; unsigned int u; } c; c.f = f;
  unsigned int r = c.u + 0x7FFFu + ((c.u >> 16) & 1u);  // RNE
  return (unsigned short)(r >> 16);
}

// ---------------- weight transpose+convert: fp32 [K][N] -> bf16 [N][K] ----------------
__global__ __launch_bounds__(256) void wtrans_kernel(
    const float* __restrict__ in, unsigned short* __restrict__ out, int K, int N)
{
  __shared__ float t[64][65];
  const int l = blockIdx.z;
  in  += (size_t)l * K * N;
  out += (size_t)l * N * K;
  const int k0 = blockIdx.x * 64, n0 = blockIdx.y * 64;
  const int tx = threadIdx.x & 63, ty = threadIdx.x >> 6;
#pragma unroll
  for (int i = 0; i < 16; ++i) {
    int r = ty + i * 4;
    t[r][tx] = in[(size_t)(k0 + r) * N + n0 + tx];
  }
  __syncthreads();
#pragma unroll
  for (int i = 0; i < 16; ++i) {
    int r = ty + i * 4;
    out[(size_t)(n0 + r) * K + k0 + tx] = f2bf(t[tx][r]);
  }
}

// ---------------- embedding + positional encoding (dual write fp32 + bf16) ----------------
__global__ __launch_bounds__(256) void embed_kernel(
    const float* __restrict__ runs, const float* __restrict__ wickets,
    const float* __restrict__ overs, const int* __restrict__ batters,
    const int* __restrict__ bowlers, const float* __restrict__ pemb,
    const float* __restrict__ Wf, const float* __restrict__ bfv,
    const float* __restrict__ qtok, float* __restrict__ x,
    unsigned short* __restrict__ xb)
{
  size_t idx = (size_t)blockIdx.x * 256 + threadIdx.x;
  const size_t total = (size_t)B_ * T_ * D_;
  if (idx >= total) return;
  int d = (int)(idx % D_);
  int t = (int)((idx / D_) % T_);
  int b = (int)(idx / ((size_t)D_ * T_));
  float val;
  if (t < S_) {
    size_t st = (size_t)b * S_ + t;
    if (d < FD_) {
      val = runs[st] * Wf[d] + wickets[st] * Wf[FD_ + d] + overs[st] * Wf[2 * FD_ + d] + bfv[d];
    } else if (d < FD_ + PD_) {
      val = pemb[(size_t)batters[st] * PD_ + (d - FD_)];
    } else {
      val = pemb[(size_t)bowlers[st] * PD_ + (d - FD_ - PD_)];
    }
  } else {
    val = qtok[d];
  }
  float div = expf((float)(2 * (d >> 1)) * (-9.210340371976184f / (float)D_));
  float ang = (float)t * div;
  val += (d & 1) ? cosf(ang) : sinf(ang);
  x[idx] = val;
  xb[idx] = f2bf(val);
}

// ---------------- bf16 MFMA GEMM (double-buffered global_load_lds prefetch) ----------------
// ACT==0: fp32 C ; ACT==1: GELU -> bf16 Cb ; ACT==2: bf16 Cb ; ACT==3: bf16 -> vt[B,H,64,T]
template<int ACT>
__global__ __launch_bounds__(256) void mfma_gemm(
    const unsigned short* __restrict__ A, const unsigned short* __restrict__ Bt,
    const float* __restrict__ bias, float* __restrict__ C,
    unsigned short* __restrict__ Cb, int N, int K)
{
  __shared__ unsigned short As[2][128 * 32];
  __shared__ unsigned short Bs[2][128 * 32];
  __shared__ unsigned short Ts[ACT == 3 ? 128 * 136 : 1];  // transpose staging (V-GEMM only)
  const int tid = threadIdx.x;
  const int m0 = blockIdx.y * 128, n0 = blockIdx.x * 128;
  const int lane = tid & 63, w = tid >> 6;
  const int wr = w >> 1, wc = w & 1;
  const int lr = lane & 15, lg = lane >> 4;

  f32x4 acc[4][4] = {};

  // staging: wave w rows [16w,16w+16) and [64+16w,..); lane l -> row 16w+(l>>2), col8 (l&3)*8
  const int srow = w * 16 + (lane >> 2);
  const int sc8 = (lane & 3) * 8;
  const unsigned short* gA0 = A + (size_t)(m0 + srow) * K + sc8;
  const unsigned short* gA1 = gA0 + (size_t)64 * K;
  const unsigned short* gB0 = Bt + (size_t)(n0 + srow) * K + sc8;
  const unsigned short* gB1 = gB0 + (size_t)64 * K;
  const int lofs0 = (w * 16) * 32;
  const int lofs1 = (64 + w * 16) * 32;

#define STAGE(buf, kk)                                                        \
  do {                                                                        \
    GLDS16(gA0 + (kk), &As[buf][lofs0]);                                      \
    GLDS16(gA1 + (kk), &As[buf][lofs1]);                                      \
    GLDS16(gB0 + (kk), &Bs[buf][lofs0]);                                      \
    GLDS16(gB1 + (kk), &Bs[buf][lofs1]);                                      \
  } while (0)

  STAGE(0, 0);
  __syncthreads();  // drains vmcnt -> buf0 valid
  int cur = 0;
  for (int k0 = 0; k0 < K; k0 += 32) {
    if (k0 + 32 < K) STAGE(cur ^ 1, k0 + 32);  // prefetch next tile (hides under MFMA)
    bf16x8 af[4], bfr[4];
#pragma unroll
    for (int f = 0; f < 4; ++f) {
      af[f]  = *(const bf16x8*)&As[cur][(wr * 64 + f * 16 + lr) * 32 + lg * 8];
      bfr[f] = *(const bf16x8*)&Bs[cur][(wc * 64 + f * 16 + lr) * 32 + lg * 8];
    }
#pragma unroll
    for (int i = 0; i < 4; ++i)
#pragma unroll
      for (int j = 0; j < 4; ++j)
        acc[i][j] = __builtin_amdgcn_mfma_f32_16x16x32_bf16(af[i], bfr[j], acc[i][j], 0, 0, 0);
    __syncthreads();  // one barrier per K-step: drains prefetch + syncs reads
    cur ^= 1;
  }
#undef STAGE

  const int crow0 = m0 + wr * 64 + lg * 4;
  const int ccol0 = n0 + wc * 64 + lr;
#pragma unroll
  for (int i = 0; i < 4; ++i) {
#pragma unroll
    for (int j = 0; j < 4; ++j) {
      const int col = ccol0 + j * 16;
      const float bcol = bias[col];
#pragma unroll
      for (int r = 0; r < 4; ++r) {
        const int row = crow0 + i * 16 + r;
        float v = acc[i][j][r] + bcol;
        if (ACT == 1) {
          v = 0.5f * v * (1.0f + erff(v * 0.70710678118654752f));
          Cb[(size_t)row * N + col] = f2bf(v);
        } else if (ACT == 2) {
          Cb[(size_t)row * N + col] = f2bf(v);
        } else if (ACT == 3) {
          // stage into LDS transpose buffer [col][row] (pad to 136 for alignment)
          Ts[(wc * 64 + j * 16 + lr) * 136 + (wr * 64 + i * 16 + lg * 4 + r)] = f2bf(v);
        } else {
          C[(size_t)row * N + col] = v;
        }
      }
    }
  }
  if (ACT == 3) {
    __syncthreads();
    // coalesced-ish store: each thread owns one col, 64 consecutive t as 8 x 16B
    const int c = tid & 127, h2 = tid >> 7;
    const int hh = (n0 + c) >> 6, hd = (n0 + c) & 63;
    const int bb = m0 >> 9, t0 = (m0 & (T_ - 1)) + h2 * 64;
    unsigned short* dst = Cb + (((size_t)bb * H_ + hh) * HD_ + hd) * T_ + t0;
#pragma unroll
    for (int e = 0; e < 8; ++e)
      *(bf16x8*)(dst + e * 8) = *(const bf16x8*)&Ts[c * 136 + h2 * 64 + e * 8];
  }
}

// ---------------- MFMA flash attention, paired 64-row Q tiles (balanced) ----------------
// block = (p, h, b), p in [0,4); processes q-tiles qt=p and qt=7-p -> 9 K-tiles/block uniform
__global__ __launch_bounds__(256) void flash_mfma_kernel(
    const unsigned short* __restrict__ q, const unsigned short* __restrict__ k,
    const unsigned short* __restrict__ vt, unsigned short* __restrict__ o,
    const int* __restrict__ batters, const int* __restrict__ bowlers,
    const float* __restrict__ rec_sp, const float* __restrict__ bow_sp,
    const float* __restrict__ bat_sp, int l)
{
  __shared__ unsigned short QPs[64 * 70];  // Q tile, later P tile (wave-private rows)
  __shared__ unsigned short Ks[64 * 70];
  __shared__ unsigned short Vs[64 * 70];   // V^T tile: [d][k]
  __shared__ int aq_s[64], ak_s[64];

  const int p = blockIdx.x, h = blockIdx.y, b = blockIdx.z;
  const int tid = threadIdx.x;
  const int w = tid >> 6, lane = tid & 63;
  const int c = lane & 15, g = lane >> 4;
  const int NT = T_ / 64;

  int mode = 0; float hs = 0.f;
  if (h == 0) { mode = 1; hs = rec_sp[l]; }
  else if (h == 1) { mode = 2; hs = bow_sp[l]; }
  else if (h == 2) { mode = 3; hs = bat_sp[l]; }
  const int* actors = (mode == 2) ? bowlers : batters;

  const int sr = tid >> 2, sch = (tid & 3) * 16;

  for (int ph = 0; ph < 2; ++ph) {
    const int qt = (ph == 0) ? p : (NT - 1 - p);
    const int q0 = qt * 64;
    __syncthreads();  // protect QPs/Ks/Vs against previous phase readers

    // stage Q tile [64 q][64 d]
    {
      const unsigned short* src = q + ((size_t)b * T_ + q0 + sr) * D_ + h * HD_ + sch;
      *(bf16x8*)&QPs[sr * 70 + sch]     = *(const bf16x8*)src;
      *(bf16x8*)&QPs[sr * 70 + sch + 8] = *(const bf16x8*)(src + 8);
    }
    if (tid < 64) {
      int qg_ = q0 + tid;
      aq_s[tid] = (mode >= 2 && qg_ < S_) ? actors[(size_t)b * S_ + qg_] : -1;
    }
    __syncthreads();

    bf16x8 af0 = *(const bf16x8*)&QPs[(w * 16 + c) * 70 + g * 8];
    bf16x8 af1 = *(const bf16x8*)&QPs[(w * 16 + c) * 70 + 32 + g * 8];
    int aq4[4];
#pragma unroll
    for (int r = 0; r < 4; ++r) aq4[r] = aq_s[w * 16 + 4 * g + r];

    float m_r[4] = {-INFINITY, -INFINITY, -INFINITY, -INFINITY};
    float l_r[4] = {0.f, 0.f, 0.f, 0.f};
    f32x4 o_acc[4] = {};

    for (int kt = 0; kt <= qt; ++kt) {
      const int k0 = kt * 64;
      __syncthreads();  // prior readers of Ks/Vs/ak_s done
      {
        const unsigned short* ksrc = k + ((size_t)b * T_ + k0 + sr) * D_ + h * HD_ + sch;
        *(bf16x8*)&Ks[sr * 70 + sch]     = *(const bf16x8*)ksrc;
        *(bf16x8*)&Ks[sr * 70 + sch + 8] = *(const bf16x8*)(ksrc + 8);
        const unsigned short* vsrc = vt + ((size_t)(b * H_ + h) * HD_ + sr) * T_ + k0 + sch;
        *(bf16x8*)&Vs[sr * 70 + sch]     = *(const bf16x8*)vsrc;
        *(bf16x8*)&Vs[sr * 70 + sch + 8] = *(const bf16x8*)(vsrc + 8);
      }
      if (tid < 64) {
        int kg_ = k0 + tid;
        ak_s[tid] = (mode >= 2 && kg_ < S_) ? actors[(size_t)b * S_ + kg_] : -1;
      }
      __syncthreads();

      if (q0 + w * 16 + 15 < k0) continue;  // wave fully causal-masked

      // ---- QK^T: S[16 q][64 k] per wave ----
      f32x4 s[4] = {};
#pragma unroll
      for (int f = 0; f < 4; ++f) {
        bf16x8 b0 = *(const bf16x8*)&Ks[(f * 16 + c) * 70 + g * 8];
        bf16x8 b1 = *(const bf16x8*)&Ks[(f * 16 + c) * 70 + 32 + g * 8];
        s[f] = __builtin_amdgcn_mfma_f32_16x16x32_bf16(af0, b0, s[f], 0, 0, 0);
        s[f] = __builtin_amdgcn_mfma_f32_16x16x32_bf16(af1, b1, s[f], 0, 0, 0);
      }

      int ak4[4];
#pragma unroll
      for (int f = 0; f < 4; ++f) ak4[f] = ak_s[f * 16 + c];

      float sv[4][4];
#pragma unroll
      for (int f = 0; f < 4; ++f) {
        const int kg = k0 + f * 16 + c;
#pragma unroll
        for (int r = 0; r < 4; ++r) {
          const int qg = q0 + w * 16 + 4 * g + r;
          float val = s[f][r] * 0.125f;
          if (mode == 1) {
            val = fmaf(hs, (float)kg * (1.0f / (float)T_), val);
          } else if (mode >= 2) {
            float eq = (qg == S_ || kg == S_) ? 1.0f : ((aq4[r] == ak4[f]) ? 1.0f : 0.0f);
            val = fmaf(hs, eq, val);
          }
          if (kg > qg) val = -INFINITY;
          sv[f][r] = val;
        }
      }
      // online softmax (row reduce across 16 lanes sharing g)
      float cr[4];
#pragma unroll
      for (int r = 0; r < 4; ++r) {
        float pm = fmaxf(fmaxf(sv[0][r], sv[1][r]), fmaxf(sv[2][r], sv[3][r]));
        pm = fmaxf(pm, __shfl_xor(pm, 1));
        pm = fmaxf(pm, __shfl_xor(pm, 2));
        pm = fmaxf(pm, __shfl_xor(pm, 4));
        pm = fmaxf(pm, __shfl_xor(pm, 8));
        float m_new = fmaxf(m_r[r], pm);
        cr[r] = __expf(m_r[r] - m_new);
        m_r[r] = m_new;
      }
      float rs[4] = {0.f, 0.f, 0.f, 0.f};
#pragma unroll
      for (int f = 0; f < 4; ++f) {
#pragma unroll
        for (int r = 0; r < 4; ++r) {
          float pv = __expf(sv[f][r] - m_r[r]);
          rs[r] += pv;
          QPs[(w * 16 + 4 * g + r) * 70 + f * 16 + c] = f2bf(pv);
        }
      }
#pragma unroll
      for (int r = 0; r < 4; ++r) {
        float t = rs[r];
        t += __shfl_xor(t, 1);
        t += __shfl_xor(t, 2);
        t += __shfl_xor(t, 4);
        t += __shfl_xor(t, 8);
        l_r[r] = l_r[r] * cr[r] + t;
#pragma unroll
        for (int f = 0; f < 4; ++f) o_acc[f][r] *= cr[r];
      }

      // ---- PV: O[16 q][64 d] += P @ V^T ----
      bf16x8 pa0 = *(const bf16x8*)&QPs[(w * 16 + c) * 70 + g * 8];
      bf16x8 pa1 = *(const bf16x8*)&QPs[(w * 16 + c) * 70 + 32 + g * 8];
#pragma unroll
      for (int f = 0; f < 4; ++f) {
        bf16x8 v0 = *(const bf16x8*)&Vs[(f * 16 + c) * 70 + g * 8];
        bf16x8 v1 = *(const bf16x8*)&Vs[(f * 16 + c) * 70 + 32 + g * 8];
        o_acc[f] = __builtin_amdgcn_mfma_f32_16x16x32_bf16(pa0, v0, o_acc[f], 0, 0, 0);
        o_acc[f] = __builtin_amdgcn_mfma_f32_16x16x32_bf16(pa1, v1, o_acc[f], 0, 0, 0);
      }
    }

    // ---- epilogue: normalize, store bf16 ----
#pragma unroll
    for (int r = 0; r < 4; ++r) {
      const float inv = 1.0f / l_r[r];
      const int row = q0 + w * 16 + 4 * g + r;
#pragma unroll
      for (int f = 0; f < 4; ++f)
        o[((size_t)b * T_ + row) * D_ + h * HD_ + f * 16 + c] = f2bf(o_acc[f][r] * inv);
    }
  }
}

// ---------------- residual add + LayerNorm (dual write fp32 + bf16) ----------------
__global__ __launch_bounds__(256) void add_ln_kernel(
    float* __restrict__ x, const float* __restrict__ y,
    const float* __restrict__ g, const float* __restrict__ be,
    unsigned short* __restrict__ xb)
{
  int row = blockIdx.x;
  int tid = threadIdx.x;
  size_t base = (size_t)row * D_;
  float v0 = x[base + tid] + y[base + tid];
  float v1 = x[base + tid + 256] + y[base + tid + 256];
  float s = v0 + v1;
  float s2 = v0 * v0 + v1 * v1;
  __shared__ float redA[4], redB[4];
#pragma unroll
  for (int off = 32; off > 0; off >>= 1) {
    s  += __shfl_down(s, off);
    s2 += __shfl_down(s2, off);
  }
  if ((tid & 63) == 0) { redA[tid >> 6] = s; redB[tid >> 6] = s2; }
  __syncthreads();
  float st  = redA[0] + redA[1] + redA[2] + redA[3];
  float s2t = redB[0] + redB[1] + redB[2] + redB[3];
  float mu = st * (1.0f / (float)D_);
  float var = s2t * (1.0f / (float)D_) - mu * mu;
  float r = rsqrtf(var + 1e-5f);
  float o0 = (v0 - mu) * r * g[tid] + be[tid];
  float o1 = (v1 - mu) * r * g[tid + 256] + be[tid + 256];
  x[base + tid]        = o0;
  x[base + tid + 256]  = o1;
  xb[base + tid]       = f2bf(o0);
  xb[base + tid + 256] = f2bf(o1);
}

// ---------------- final: out[b,:] = x[b,T-1,:] @ Wout + bout ----------------
__global__ __launch_bounds__(256) void final_kernel(
    const float* __restrict__ x, const float* __restrict__ Wout,
    const float* __restrict__ bout, float* __restrict__ out)
{
  __shared__ float xs[D_];
  int b = blockIdx.x;
  int n = blockIdx.y * 256 + threadIdx.x;
  const float* xr = x + ((size_t)b * T_ + (T_ - 1)) * D_;
  xs[threadIdx.x] = xr[threadIdx.x];
  xs[threadIdx.x + 256] = xr[threadIdx.x + 256];
  __syncthreads();
  float acc = bout[n];
  for (int kk = 0; kk < D_; ++kk)
    acc = fmaf(xs[kk], Wout[(size_t)kk * D_ + n], acc);
  out[(size_t)b * D_ + n] = acc;
}

extern "C" void kernel_launch(void* const* d_in, const int* in_sizes, int n_in,
                              void* d_out, int out_size, void* d_ws, size_t ws_size,
                              hipStream_t stream)
{
  const float* runs    = (const float*)d_in[0];
  const float* wickets = (const float*)d_in[1];
  const float* overs   = (const float*)d_in[2];
  const int*   batters = (const int*)d_in[3];
  const int*   bowlers = (const int*)d_in[4];
  const float* pemb    = (const float*)d_in[5];
  const float* Wf      = (const float*)d_in[6];
  const float* bfv     = (const float*)d_in[7];
  const float* qtok    = (const float*)d_in[8];
  const float* Wq      = (const float*)d_in[9];
  const float* bq      = (const float*)d_in[10];
  const float* Wk      = (const float*)d_in[11];
  const float* bk      = (const float*)d_in[12];
  const float* Wv      = (const float*)d_in[13];
  const float* bv      = (const float*)d_in[14];
  const float* Wo      = (const float*)d_in[15];
  const float* bo      = (const float*)d_in[16];
  const float* rec_s   = (const float*)d_in[17];
  const float* bow_s   = (const float*)d_in[18];
  const float* bat_s   = (const float*)d_in[19];
  const float* W1      = (const float*)d_in[20];
  const float* b1      = (const float*)d_in[21];
  const float* W2      = (const float*)d_in[22];
  const float* b2      = (const float*)d_in[23];
  const float* g1      = (const float*)d_in[24];
  const float* be1     = (const float*)d_in[25];
  const float* g2      = (const float*)d_in[26];
  const float* be2     = (const float*)d_in[27];
  const float* Wout    = (const float*)d_in[28];
  const float* bout    = (const float*)d_in[29];

  float* ws = (float*)d_ws;
  const size_t n1 = (size_t)B_ * T_ * D_;  // 8M elements
  float* x  = ws;                                   // n1 f32
  float* yb = ws + n1;                              // n1 f32
  unsigned short* xb   = (unsigned short*)(ws + 2 * n1);
  unsigned short* qb16 = xb + n1;
  unsigned short* kb16 = qb16 + n1;
  unsigned short* vb16 = kb16 + n1;   // unused (V goes straight to vt)
  unsigned short* vt   = vb16 + n1;
  unsigned short* ob   = vt + n1;
  unsigned short* wt   = ob + n1;
  unsigned short* hb   = qb16;  // FFN hidden aliases qb16..vt (exactly 4*n1 shorts)

  const size_t wsz = (size_t)L_ * D_ * D_;
  unsigned short* wtq = wt;
  unsigned short* wtk = wtq + wsz;
  unsigned short* wtv = wtk + wsz;
  unsigned short* wto = wtv + wsz;
  unsigned short* wt1 = wto + wsz;
  unsigned short* wt2 = wt1 + (size_t)L_ * D_ * DFF_;

  const int M = B_ * T_;
  dim3 blk(256);

  wtrans_kernel<<<dim3(8, 8, L_),  blk, 0, stream>>>(Wq, wtq, D_, D_);
  wtrans_kernel<<<dim3(8, 8, L_),  blk, 0, stream>>>(Wk, wtk, D_, D_);
  wtrans_kernel<<<dim3(8, 8, L_),  blk, 0, stream>>>(Wv, wtv, D_, D_);
  wtrans_kernel<<<dim3(8, 8, L_),  blk, 0, stream>>>(Wo, wto, D_, D_);
  wtrans_kernel<<<dim3(8, 32, L_), blk, 0, stream>>>(W1, wt1, D_, DFF_);
  wtrans_kernel<<<dim3(32, 8, L_), blk, 0, stream>>>(W2, wt2, DFF_, D_);

  {
    size_t total = (size_t)B_ * T_ * D_;
    int nb = (int)((total + 255) / 256);
    embed_kernel<<<nb, blk, 0, stream>>>(runs, wickets, overs, batters, bowlers,
                                         pemb, Wf, bfv, qtok, x, xb);
  }

  for (int l = 0; l < L_; ++l) {
    mfma_gemm<2><<<dim3(D_ / 128, M / 128), blk, 0, stream>>>(
        xb, wtq + (size_t)l * D_ * D_, bq + l * D_, nullptr, qb16, D_, D_);
    mfma_gemm<2><<<dim3(D_ / 128, M / 128), blk, 0, stream>>>(
        xb, wtk + (size_t)l * D_ * D_, bk + l * D_, nullptr, kb16, D_, D_);
    mfma_gemm<3><<<dim3(D_ / 128, M / 128), blk, 0, stream>>>(
        xb, wtv + (size_t)l * D_ * D_, bv + l * D_, nullptr, vt, D_, D_);

    flash_mfma_kernel<<<dim3(T_ / 128, H_, B_), blk, 0, stream>>>(
        qb16, kb16, vt, ob, batters, bowlers, rec_s, bow_s, bat_s, l);

    mfma_gemm<0><<<dim3(D_ / 128, M / 128), blk, 0, stream>>>(
        ob, wto + (size_t)l * D_ * D_, bo + l * D_, yb, nullptr, D_, D_);
    add_ln_kernel<<<M, blk, 0, stream>>>(x, yb, g1 + l * D_, be1 + l * D_, xb);

    mfma_gemm<1><<<dim3(DFF_ / 128, M / 128), blk, 0, stream>>>(
        xb, wt1 + (size_t)l * D_ * DFF_, b1 + l * DFF_, nullptr, hb, DFF_, D_);
    mfma_gemm<0><<<dim3(D_ / 128, M / 128), blk, 0, stream>>>(
        hb, wt2 + (size_t)l * DFF_ * D_, b2 + l * D_, yb, nullptr, D_, DFF_);
    add_ln_kernel<<<M, blk, 0, stream>>>(x, yb, g2 + l * D_, be2 + l * D_, xb);
  }

  final_kernel<<<dim3(B_, D_ / 256), blk, 0, stream>>>(x, Wout, bout, (float*)d_out);
}

// Round 9
// 1348.781 us; speedup vs baseline: 1.1518x; 1.0371x over previous
//
#include <hip/hip_runtime.h>
#include <math.h>

#define B_ 32
#define S_ 511
#define T_ 512
#define D_ 512
#define H_ 8
#define HD_ 64
#define L_ 4
#define P_ 501
#define PD_ 32
#define FD_ 448
#define DFF_ 2048

typedef __attribute__((ext_vector_type(8))) short bf16x8;
typedef __attribute__((ext_vector_type(4))) float f32x4;

#define GLDS16(gp, lp) __builtin_amdgcn_global_load_lds(                      \
    (const __attribute__((address_space(1))) void*)(gp),                      \
    (__attribute__((address_space(3))) void*)(lp), 16, 0, 0)

__device__ __forceinline__ unsigned short f2bf(float f) {
  union { float f; unsigned int u; } c; c.f = f;
  unsigned int r = c.u + 0x7FFFu + ((c.u >> 16) & 1u);  // RNE
  return (unsigned short)(r >> 16);
}

// ---- weight transpose+convert: fp32 [K][N] -> bf16 rows [nofs..nofs+N) of [..][K] ----
__global__ __launch_bounds__(256) void wtrans_kernel(
    const float* __restrict__ in, unsigned short* __restrict__ out, int K, int N,
    size_t lstride, int nofs)
{
  __shared__ float t[64][65];
  const int l = blockIdx.z;
  in  += (size_t)l * K * N;
  out += (size_t)l * lstride + (size_t)nofs * K;
  const int k0 = blockIdx.x * 64, n0 = blockIdx.y * 64;
  const int tx = threadIdx.x & 63, ty = threadIdx.x >> 6;
#pragma unroll
  for (int i = 0; i < 16; ++i) {
    int r = ty + i * 4;
    t[r][tx] = in[(size_t)(k0 + r) * N + n0 + tx];
  }
  __syncthreads();
#pragma unroll
  for (int i = 0; i < 16; ++i) {
    int r = ty + i * 4;
    out[(size_t)(n0 + r) * K + k0 + tx] = f2bf(t[tx][r]);
  }
}

// ---------------- embedding + positional encoding (dual write fp32 + bf16) ----------------
__global__ __launch_bounds__(256) void embed_kernel(
    const float* __restrict__ runs, const float* __restrict__ wickets,
    const float* __restrict__ overs, const int* __restrict__ batters,
    const int* __restrict__ bowlers, const float* __restrict__ pemb,
    const float* __restrict__ Wf, const float* __restrict__ bfv,
    const float* __restrict__ qtok, float* __restrict__ x,
    unsigned short* __restrict__ xb)
{
  size_t idx = (size_t)blockIdx.x * 256 + threadIdx.x;
  const size_t total = (size_t)B_ * T_ * D_;
  if (idx >= total) return;
  int d = (int)(idx % D_);
  int t = (int)((idx / D_) % T_);
  int b = (int)(idx / ((size_t)D_ * T_));
  float val;
  if (t < S_) {
    size_t st = (size_t)b * S_ + t;
    if (d < FD_) {
      val = runs[st] * Wf[d] + wickets[st] * Wf[FD_ + d] + overs[st] * Wf[2 * FD_ + d] + bfv[d];
    } else if (d < FD_ + PD_) {
      val = pemb[(size_t)batters[st] * PD_ + (d - FD_)];
    } else {
      val = pemb[(size_t)bowlers[st] * PD_ + (d - FD_ - PD_)];
    }
  } else {
    val = qtok[d];
  }
  float div = expf((float)(2 * (d >> 1)) * (-9.210340371976184f / (float)D_));
  float ang = (float)t * div;
  val += (d & 1) ? cosf(ang) : sinf(ang);
  x[idx] = val;
  xb[idx] = f2bf(val);
}

// ---------------- bf16 MFMA GEMM (double-buffered global_load_lds prefetch) ----------------
// ACT==0: fp32 C ; ACT==1: GELU->bf16 Cb ; ACT==2: bf16 Cb ; ACT==3: bf16 -> vt[B,H,64,T]
// ACT==4: bf16 Cb with split bias (cols <512 -> bias, >=512 -> bias2); fused QK (N=1024)
template<int ACT>
__global__ __launch_bounds__(256) void mfma_gemm(
    const unsigned short* __restrict__ A, const unsigned short* __restrict__ Bt,
    const float* __restrict__ bias, float* __restrict__ C,
    unsigned short* __restrict__ Cb, int N, int K, const float* __restrict__ bias2)
{
  __shared__ unsigned short As[2][128 * 32];
  __shared__ unsigned short Bs[2][128 * 32];
  __shared__ unsigned short Ts[ACT == 3 ? 128 * 136 : 1];  // transpose staging (V-GEMM only)
  const int tid = threadIdx.x;
  const int m0 = blockIdx.y * 128, n0 = blockIdx.x * 128;
  const int lane = tid & 63, w = tid >> 6;
  const int wr = w >> 1, wc = w & 1;
  const int lr = lane & 15, lg = lane >> 4;

  f32x4 acc[4][4] = {};

  const int srow = w * 16 + (lane >> 2);
  const int sc8 = (lane & 3) * 8;
  const unsigned short* gA0 = A + (size_t)(m0 + srow) * K + sc8;
  const unsigned short* gA1 = gA0 + (size_t)64 * K;
  const unsigned short* gB0 = Bt + (size_t)(n0 + srow) * K + sc8;
  const unsigned short* gB1 = gB0 + (size_t)64 * K;
  const int lofs0 = (w * 16) * 32;
  const int lofs1 = (64 + w * 16) * 32;

#define STAGE(buf, kk)                                                        \
  do {                                                                        \
    GLDS16(gA0 + (kk), &As[buf][lofs0]);                                      \
    GLDS16(gA1 + (kk), &As[buf][lofs1]);                                      \
    GLDS16(gB0 + (kk), &Bs[buf][lofs0]);                                      \
    GLDS16(gB1 + (kk), &Bs[buf][lofs1]);                                      \
  } while (0)

  STAGE(0, 0);
  __syncthreads();  // drains vmcnt -> buf0 valid
  int cur = 0;
  for (int k0 = 0; k0 < K; k0 += 32) {
    if (k0 + 32 < K) STAGE(cur ^ 1, k0 + 32);  // prefetch next tile (hides under MFMA)
    bf16x8 af[4], bfr[4];
#pragma unroll
    for (int f = 0; f < 4; ++f) {
      af[f]  = *(const bf16x8*)&As[cur][(wr * 64 + f * 16 + lr) * 32 + lg * 8];
      bfr[f] = *(const bf16x8*)&Bs[cur][(wc * 64 + f * 16 + lr) * 32 + lg * 8];
    }
#pragma unroll
    for (int i = 0; i < 4; ++i)
#pragma unroll
      for (int j = 0; j < 4; ++j)
        acc[i][j] = __builtin_amdgcn_mfma_f32_16x16x32_bf16(af[i], bfr[j], acc[i][j], 0, 0, 0);
    __syncthreads();  // one barrier per K-step: drains prefetch + syncs reads
    cur ^= 1;
  }
#undef STAGE

  const int crow0 = m0 + wr * 64 + lg * 4;
  const int ccol0 = n0 + wc * 64 + lr;
#pragma unroll
  for (int i = 0; i < 4; ++i) {
#pragma unroll
    for (int j = 0; j < 4; ++j) {
      const int col = ccol0 + j * 16;
      const float bcol = (ACT == 4) ? ((col < 512) ? bias[col] : bias2[col - 512])
                                    : bias[col];
#pragma unroll
      for (int r = 0; r < 4; ++r) {
        const int row = crow0 + i * 16 + r;
        float v = acc[i][j][r] + bcol;
        if (ACT == 1) {
          v = 0.5f * v * (1.0f + erff(v * 0.70710678118654752f));
          Cb[(size_t)row * N + col] = f2bf(v);
        } else if (ACT == 2 || ACT == 4) {
          Cb[(size_t)row * N + col] = f2bf(v);
        } else if (ACT == 3) {
          Ts[(wc * 64 + j * 16 + lr) * 136 + (wr * 64 + i * 16 + lg * 4 + r)] = f2bf(v);
        } else {
          C[(size_t)row * N + col] = v;
        }
      }
    }
  }
  if (ACT == 3) {
    __syncthreads();
    const int c = tid & 127, h2 = tid >> 7;
    const int hh = (n0 + c) >> 6, hd = (n0 + c) & 63;
    const int bb = m0 >> 9, t0 = (m0 & (T_ - 1)) + h2 * 64;
    unsigned short* dst = Cb + (((size_t)bb * H_ + hh) * HD_ + hd) * T_ + t0;
#pragma unroll
    for (int e = 0; e < 8; ++e)
      *(bf16x8*)(dst + e * 8) = *(const bf16x8*)&Ts[c * 136 + h2 * 64 + e * 8];
  }
}

// ---------------- MFMA flash attention: paired tiles + K/V double-buffer ----------------
// block = (p, h, b), p in [0,4); q-tiles qt=p and qt=7-p -> 9 K-tiles/block uniform.
// Per K-tile: prefetch next K/V into regs BEFORE compute, ds_write after, 1 barrier.
__global__ __launch_bounds__(256) void flash_mfma_kernel(
    const unsigned short* __restrict__ qk, const unsigned short* __restrict__ vt,
    unsigned short* __restrict__ o,
    const int* __restrict__ batters, const int* __restrict__ bowlers,
    const float* __restrict__ rec_sp, const float* __restrict__ bow_sp,
    const float* __restrict__ bat_sp, int l)
{
  __shared__ unsigned short QPs[64 * 70];   // Q tile, later P tile (wave-private rows)
  __shared__ unsigned short Ks[2][64 * 70];
  __shared__ unsigned short Vs[2][64 * 70]; // V^T tile: [d][k]
  __shared__ int aq_s[64], ak_s[2][64];

  const int p = blockIdx.x, h = blockIdx.y, b = blockIdx.z;
  const int tid = threadIdx.x;
  const int w = tid >> 6, lane = tid & 63;
  const int c = lane & 15, g = lane >> 4;
  const int NT = T_ / 64;

  int mode = 0; float hs = 0.f;
  if (h == 0) { mode = 1; hs = rec_sp[l]; }
  else if (h == 1) { mode = 2; hs = bow_sp[l]; }
  else if (h == 2) { mode = 3; hs = bat_sp[l]; }
  const int* actors = (mode == 2) ? bowlers : batters;

  const int sr = tid >> 2, sch = (tid & 3) * 16;
  const unsigned short* qbase = qk + (size_t)b * T_ * 1024 + h * HD_;  // row stride 1024
  const unsigned short* kbase = qbase + 512;
  const unsigned short* vbase = vt + ((size_t)(b * H_ + h) * HD_ + sr) * T_;

  for (int ph = 0; ph < 2; ++ph) {
    const int qt = (ph == 0) ? p : (NT - 1 - p);
    const int q0 = qt * 64;
    __syncthreads();  // protect QPs/Ks/Vs against previous phase readers

    // stage Q tile + K/V tile kt=0 into buf0
    {
      const unsigned short* src = qbase + (size_t)(q0 + sr) * 1024 + sch;
      *(bf16x8*)&QPs[sr * 70 + sch]     = *(const bf16x8*)src;
      *(bf16x8*)&QPs[sr * 70 + sch + 8] = *(const bf16x8*)(src + 8);
      const unsigned short* ksrc = kbase + (size_t)sr * 1024 + sch;  // k0 = 0
      *(bf16x8*)&Ks[0][sr * 70 + sch]     = *(const bf16x8*)ksrc;
      *(bf16x8*)&Ks[0][sr * 70 + sch + 8] = *(const bf16x8*)(ksrc + 8);
      const unsigned short* vsrc = vbase + sch;
      *(bf16x8*)&Vs[0][sr * 70 + sch]     = *(const bf16x8*)vsrc;
      *(bf16x8*)&Vs[0][sr * 70 + sch + 8] = *(const bf16x8*)(vsrc + 8);
    }
    if (tid < 64) {
      int qg_ = q0 + tid;
      aq_s[tid] = (mode >= 2 && qg_ < S_) ? actors[(size_t)b * S_ + qg_] : -1;
      ak_s[0][tid] = (mode >= 2 && tid < S_) ? actors[(size_t)b * S_ + tid] : -1;
    }
    __syncthreads();

    bf16x8 af0 = *(const bf16x8*)&QPs[(w * 16 + c) * 70 + g * 8];
    bf16x8 af1 = *(const bf16x8*)&QPs[(w * 16 + c) * 70 + 32 + g * 8];
    int aq4[4];
#pragma unroll
    for (int r = 0; r < 4; ++r) aq4[r] = aq_s[w * 16 + 4 * g + r];

    float m_r[4] = {-INFINITY, -INFINITY, -INFINITY, -INFINITY};
    float l_r[4] = {0.f, 0.f, 0.f, 0.f};
    f32x4 o_acc[4] = {};
    int cur = 0;

    for (int kt = 0; kt <= qt; ++kt) {
      const int k0 = kt * 64;
      const bool has_next = kt < qt;
      // ---- prefetch next K/V tile into registers (latency hidden under compute) ----
      bf16x8 kr0, kr1, vr0, vr1;
      int akn = -1;
      if (has_next) {
        const int k0n = k0 + 64;
        const unsigned short* ksrc = kbase + (size_t)(k0n + sr) * 1024 + sch;
        kr0 = *(const bf16x8*)ksrc;
        kr1 = *(const bf16x8*)(ksrc + 8);
        const unsigned short* vsrc = vbase + k0n + sch;
        vr0 = *(const bf16x8*)vsrc;
        vr1 = *(const bf16x8*)(vsrc + 8);
        if (tid < 64) {
          int kg_ = k0n + tid;
          akn = (mode >= 2 && kg_ < S_) ? actors[(size_t)b * S_ + kg_] : -1;
        }
      }

      if (q0 + w * 16 + 15 >= k0) {  // wave has unmasked rows for this K tile
        // ---- QK^T: S[16 q][64 k] per wave ----
        f32x4 s[4] = {};
#pragma unroll
        for (int f = 0; f < 4; ++f) {
          bf16x8 b0 = *(const bf16x8*)&Ks[cur][(f * 16 + c) * 70 + g * 8];
          bf16x8 b1 = *(const bf16x8*)&Ks[cur][(f * 16 + c) * 70 + 32 + g * 8];
          s[f] = __builtin_amdgcn_mfma_f32_16x16x32_bf16(af0, b0, s[f], 0, 0, 0);
          s[f] = __builtin_amdgcn_mfma_f32_16x16x32_bf16(af1, b1, s[f], 0, 0, 0);
        }
        int ak4[4];
#pragma unroll
        for (int f = 0; f < 4; ++f) ak4[f] = ak_s[cur][f * 16 + c];

        float sv[4][4];
#pragma unroll
        for (int f = 0; f < 4; ++f) {
          const int kg = k0 + f * 16 + c;
#pragma unroll
          for (int r = 0; r < 4; ++r) {
            const int qg = q0 + w * 16 + 4 * g + r;
            float val = s[f][r] * 0.125f;
            if (mode == 1) {
              val = fmaf(hs, (float)kg * (1.0f / (float)T_), val);
            } else if (mode >= 2) {
              float eq = (qg == S_ || kg == S_) ? 1.0f : ((aq4[r] == ak4[f]) ? 1.0f : 0.0f);
              val = fmaf(hs, eq, val);
            }
            if (kg > qg) val = -INFINITY;
            sv[f][r] = val;
          }
        }
        // online softmax (row reduce across 16 lanes sharing g)
        float cr[4];
#pragma unroll
        for (int r = 0; r < 4; ++r) {
          float pm = fmaxf(fmaxf(sv[0][r], sv[1][r]), fmaxf(sv[2][r], sv[3][r]));
          pm = fmaxf(pm, __shfl_xor(pm, 1));
          pm = fmaxf(pm, __shfl_xor(pm, 2));
          pm = fmaxf(pm, __shfl_xor(pm, 4));
          pm = fmaxf(pm, __shfl_xor(pm, 8));
          float m_new = fmaxf(m_r[r], pm);
          cr[r] = __expf(m_r[r] - m_new);
          m_r[r] = m_new;
        }
        float rs[4] = {0.f, 0.f, 0.f, 0.f};
#pragma unroll
        for (int f = 0; f < 4; ++f) {
#pragma unroll
          for (int r = 0; r < 4; ++r) {
            float pv = __expf(sv[f][r] - m_r[r]);
            rs[r] += pv;
            QPs[(w * 16 + 4 * g + r) * 70 + f * 16 + c] = f2bf(pv);
          }
        }
#pragma unroll
        for (int r = 0; r < 4; ++r) {
          float t = rs[r];
          t += __shfl_xor(t, 1);
          t += __shfl_xor(t, 2);
          t += __shfl_xor(t, 4);
          t += __shfl_xor(t, 8);
          l_r[r] = l_r[r] * cr[r] + t;
#pragma unroll
          for (int f = 0; f < 4; ++f) o_acc[f][r] *= cr[r];
        }
        // ---- PV: O[16 q][64 d] += P @ V^T ----
        bf16x8 pa0 = *(const bf16x8*)&QPs[(w * 16 + c) * 70 + g * 8];
        bf16x8 pa1 = *(const bf16x8*)&QPs[(w * 16 + c) * 70 + 32 + g * 8];
#pragma unroll
        for (int f = 0; f < 4; ++f) {
          bf16x8 v0 = *(const bf16x8*)&Vs[cur][(f * 16 + c) * 70 + g * 8];
          bf16x8 v1 = *(const bf16x8*)&Vs[cur][(f * 16 + c) * 70 + 32 + g * 8];
          o_acc[f] = __builtin_amdgcn_mfma_f32_16x16x32_bf16(pa0, v0, o_acc[f], 0, 0, 0);
          o_acc[f] = __builtin_amdgcn_mfma_f32_16x16x32_bf16(pa1, v1, o_acc[f], 0, 0, 0);
        }
      }

      if (has_next) {
        // write prefetched tile into the other buffer; prior readers of it finished
        // before the barrier that ended iteration kt-1.
        *(bf16x8*)&Ks[cur ^ 1][sr * 70 + sch]     = kr0;
        *(bf16x8*)&Ks[cur ^ 1][sr * 70 + sch + 8] = kr1;
        *(bf16x8*)&Vs[cur ^ 1][sr * 70 + sch]     = vr0;
        *(bf16x8*)&Vs[cur ^ 1][sr * 70 + sch + 8] = vr1;
        if (tid < 64) ak_s[cur ^ 1][tid] = akn;
        __syncthreads();  // single barrier per K-tile
        cur ^= 1;
      }
    }

    // ---- epilogue: normalize, store bf16 ----
#pragma unroll
    for (int r = 0; r < 4; ++r) {
      const float inv = 1.0f / l_r[r];
      const int row = q0 + w * 16 + 4 * g + r;
#pragma unroll
      for (int f = 0; f < 4; ++f)
        o[((size_t)b * T_ + row) * D_ + h * HD_ + f * 16 + c] = f2bf(o_acc[f][r] * inv);
    }
  }
}

// ---------------- residual add + LayerNorm (dual write fp32 + bf16) ----------------
__global__ __launch_bounds__(256) void add_ln_kernel(
    float* __restrict__ x, const float* __restrict__ y,
    const float* __restrict__ g, const float* __restrict__ be,
    unsigned short* __restrict__ xb)
{
  int row = blockIdx.x;
  int tid = threadIdx.x;
  size_t base = (size_t)row * D_;
  float v0 = x[base + tid] + y[base + tid];
  float v1 = x[base + tid + 256] + y[base + tid + 256];
  float s = v0 + v1;
  float s2 = v0 * v0 + v1 * v1;
  __shared__ float redA[4], redB[4];
#pragma unroll
  for (int off = 32; off > 0; off >>= 1) {
    s  += __shfl_down(s, off);
    s2 += __shfl_down(s2, off);
  }
  if ((tid & 63) == 0) { redA[tid >> 6] = s; redB[tid >> 6] = s2; }
  __syncthreads();
  float st  = redA[0] + redA[1] + redA[2] + redA[3];
  float s2t = redB[0] + redB[1] + redB[2] + redB[3];
  float mu = st * (1.0f / (float)D_);
  float var = s2t * (1.0f / (float)D_) - mu * mu;
  float r = rsqrtf(var + 1e-5f);
  float o0 = (v0 - mu) * r * g[tid] + be[tid];
  float o1 = (v1 - mu) * r * g[tid + 256] + be[tid + 256];
  x[base + tid]        = o0;
  x[base + tid + 256]  = o1;
  xb[base + tid]       = f2bf(o0);
  xb[base + tid + 256] = f2bf(o1);
}

// ---------------- final: out[b,:] = x[b,T-1,:] @ Wout + bout ----------------
__global__ __launch_bounds__(256) void final_kernel(
    const float* __restrict__ x, const float* __restrict__ Wout,
    const float* __restrict__ bout, float* __restrict__ out)
{
  __shared__ float xs[D_];
  int b = blockIdx.x;
  int n = blockIdx.y * 256 + threadIdx.x;
  const float* xr = x + ((size_t)b * T_ + (T_ - 1)) * D_;
  xs[threadIdx.x] = xr[threadIdx.x];
  xs[threadIdx.x + 256] = xr[threadIdx.x + 256];
  __syncthreads();
  float acc = bout[n];
  for (int kk = 0; kk < D_; ++kk)
    acc = fmaf(xs[kk], Wout[(size_t)kk * D_ + n], acc);
  out[(size_t)b * D_ + n] = acc;
}

extern "C" void kernel_launch(void* const* d_in, const int* in_sizes, int n_in,
                              void* d_out, int out_size, void* d_ws, size_t ws_size,
                              hipStream_t stream)
{
  const float* runs    = (const float*)d_in[0];
  const float* wickets = (const float*)d_in[1];
  const float* overs   = (const float*)d_in[2];
  const int*   batters = (const int*)d_in[3];
  const int*   bowlers = (const int*)d_in[4];
  const float* pemb    = (const float*)d_in[5];
  const float* Wf      = (const float*)d_in[6];
  const float* bfv     = (const float*)d_in[7];
  const float* qtok    = (const float*)d_in[8];
  const float* Wq      = (const float*)d_in[9];
  const float* bq      = (const float*)d_in[10];
  const float* Wk      = (const float*)d_in[11];
  const float* bk      = (const float*)d_in[12];
  const float* Wv      = (const float*)d_in[13];
  const float* bv      = (const float*)d_in[14];
  const float* Wo      = (const float*)d_in[15];
  const float* bo      = (const float*)d_in[16];
  const float* rec_s   = (const float*)d_in[17];
  const float* bow_s   = (const float*)d_in[18];
  const float* bat_s   = (const float*)d_in[19];
  const float* W1      = (const float*)d_in[20];
  const float* b1      = (const float*)d_in[21];
  const float* W2      = (const float*)d_in[22];
  const float* b2      = (const float*)d_in[23];
  const float* g1      = (const float*)d_in[24];
  const float* be1     = (const float*)d_in[25];
  const float* g2      = (const float*)d_in[26];
  const float* be2     = (const float*)d_in[27];
  const float* Wout    = (const float*)d_in[28];
  const float* bout    = (const float*)d_in[29];

  float* ws = (float*)d_ws;
  const size_t n1 = (size_t)B_ * T_ * D_;  // 8M elements
  float* x  = ws;                                   // n1 f32
  float* yb = ws + n1;                              // n1 f32
  unsigned short* xb = (unsigned short*)(ws + 2 * n1);
  unsigned short* qkb = xb + n1;     // fused QK output [M][1024] (2*n1 shorts)
  unsigned short* vt  = qkb + 2 * n1;
  unsigned short* ob  = vt + n1;
  unsigned short* wt  = ob + n1;
  unsigned short* hb  = qkb;  // FFN hidden aliases qkb+vt+ob (exactly 4*n1 shorts)

  const size_t qk_lstride = (size_t)1024 * 512;      // fused QK weights per layer
  unsigned short* wqk = wt;
  unsigned short* wtv = wqk + (size_t)L_ * qk_lstride;
  unsigned short* wto = wtv + (size_t)L_ * D_ * D_;
  unsigned short* wt1 = wto + (size_t)L_ * D_ * D_;
  unsigned short* wt2 = wt1 + (size_t)L_ * D_ * DFF_;

  const int M = B_ * T_;
  dim3 blk(256);

  wtrans_kernel<<<dim3(8, 8, L_),  blk, 0, stream>>>(Wq, wqk, D_, D_, qk_lstride, 0);
  wtrans_kernel<<<dim3(8, 8, L_),  blk, 0, stream>>>(Wk, wqk, D_, D_, qk_lstride, 512);
  wtrans_kernel<<<dim3(8, 8, L_),  blk, 0, stream>>>(Wv, wtv, D_, D_, (size_t)D_ * D_, 0);
  wtrans_kernel<<<dim3(8, 8, L_),  blk, 0, stream>>>(Wo, wto, D_, D_, (size_t)D_ * D_, 0);
  wtrans_kernel<<<dim3(8, 32, L_), blk, 0, stream>>>(W1, wt1, D_, DFF_, (size_t)D_ * DFF_, 0);
  wtrans_kernel<<<dim3(32, 8, L_), blk, 0, stream>>>(W2, wt2, DFF_, D_, (size_t)DFF_ * D_, 0);

  {
    size_t total = (size_t)B_ * T_ * D_;
    int nb = (int)((total + 255) / 256);
    embed_kernel<<<nb, blk, 0, stream>>>(runs, wickets, overs, batters, bowlers,
                                         pemb, Wf, bfv, qtok, x, xb);
  }

  for (int l = 0; l < L_; ++l) {
    // fused Q+K projection -> qkb [M][1024]
    mfma_gemm<4><<<dim3(1024 / 128, M / 128), blk, 0, stream>>>(
        xb, wqk + (size_t)l * qk_lstride, bq + l * D_, nullptr, qkb, 1024, D_,
        bk + l * D_);
    // V projection -> vt [B,H,64,T]
    mfma_gemm<3><<<dim3(D_ / 128, M / 128), blk, 0, stream>>>(
        xb, wtv + (size_t)l * D_ * D_, bv + l * D_, nullptr, vt, D_, D_, nullptr);

    flash_mfma_kernel<<<dim3(T_ / 128, H_, B_), blk, 0, stream>>>(
        qkb, vt, ob, batters, bowlers, rec_s, bow_s, bat_s, l);

    mfma_gemm<0><<<dim3(D_ / 128, M / 128), blk, 0, stream>>>(
        ob, wto + (size_t)l * D_ * D_, bo + l * D_, yb, nullptr, D_, D_, nullptr);
    add_ln_kernel<<<M, blk, 0, stream>>>(x, yb, g1 + l * D_, be1 + l * D_, xb);

    mfma_gemm<1><<<dim3(DFF_ / 128, M / 128), blk, 0, stream>>>(
        xb, wt1 + (size_t)l * D_ * DFF_, b1 + l * DFF_, nullptr, hb, DFF_, D_, nullptr);
    mfma_gemm<0><<<dim3(D_ / 128, M / 128), blk, 0, stream>>>(
        hb, wt2 + (size_t)l * DFF_ * D_, b2 + l * D_, yb, nullptr, D_, DFF_, nullptr);
    add_ln_kernel<<<M, blk, 0, stream>>>(x, yb, g2 + l * D_, be2 + l * D_, xb);
  }

  final_kernel<<<dim3(B_, D_ / 256), blk, 0, stream>>>(x, Wout, bout, (float*)d_out);
}